// Round 16
// baseline (2154.960 us; speedup 1.0000x reference)
//
#include <hip/hip_runtime.h>
#include <hip/hip_bf16.h>

typedef __bf16 bf16x8 __attribute__((ext_vector_type(8)));
typedef float f32x4 __attribute__((ext_vector_type(4)));

static constexpr int NT = 32768;  // S*B tokens
static constexpr int D_ = 512;
static constexpr int D3 = 1536;
static constexpr int DF = 2048;
static constexpr int L_ = 6;

#define AS1 __attribute__((address_space(1)))
#define AS3 __attribute__((address_space(3)))

__device__ __forceinline__ void gload_lds16(const void* g, void* l) {
  __builtin_amdgcn_global_load_lds((const AS1 void*)g, (AS3 void*)l, 16, 0, 0);
}

// ===== 128x128 GEMM, BK=128/phase: A via LDS (2x32KB dbuf), B from global ==
// 4 waves (2M x 2N), per-wave 64x64 (acc 4x4). Phase = 2 K-tiles of 64:
//   phase ph (p=ph&1): [stage(p^1, next 2 K-tiles): 8 gloads] sched_barrier
//     for sub in {0,1}: [af: 8 ds_reads from buf p sub] [8 B gloads + 32 MFMA]
//   close: vmcnt(16) + lgkmcnt(0) + s_barrier      (one barrier per 128 K)
// RAW: the 8 stage gloads are the phase's OLDEST VMEM ops; every B value is
// consumed by this phase's MFMAs, so the compiler's counted wait on the last
// B (in-order VMEM retire) already drains the stages before any wave reaches
// the barrier; vmcnt(16) (16 = B loads/phase) is belt-and-suspenders.
// WAR: each wave's ds_reads drain at its lgkmcnt(0) before the barrier; the
// buffer is re-staged only in the next phase, after that barrier.
// B' layout (convs<>, verified r11/r15): row r, col c of an N x K weight:
//   ((r>>6)*(K>>6)+(c>>6))*4096 + (((r>>4)&3)*2+((c>>5)&1))*512
//   + ((c>>3)&3)*128 + (r&15)*8 + (c&7)          [ELEMENT offsets]
// -> wave wc's frag (n,ks) at K-tile kt: 1KB contiguous at
//    Wp + ((tn0>>6)+wc)*NKT*4096 + kt*4096 + (n*2+ks)*512 elems + lane*8.
template<int K, int NTN, bool RELU>
__global__ __launch_bounds__(256, 2) void gemm2(
    const __hip_bfloat16* __restrict__ A,
    const __hip_bfloat16* __restrict__ Wp,
    const float* __restrict__ bias,
    __hip_bfloat16* __restrict__ Cout) {
  __shared__ __align__(16) char lds[65536];
  const int t = threadIdx.x;
  const int l = t & 63, w = t >> 6;       // 4 waves
  const int lrow = l & 15, lhi = l >> 4;
  const int wr = w >> 1, wc = w & 1;      // 2M x 2N

  const int lin = blockIdx.x;
  const int wg = (lin & 7) * ((int)gridDim.x >> 3) + (lin >> 3);
  const int tm0 = (wg / NTN) * 128, tn0 = (wg % NTN) * 128;

  constexpr int NKT = K / 64;
  constexpr int NP = NKT / 2;   // phases (BK=128 each)
  constexpr int N = NTN * 128;

  const int srow = t >> 3;  // 0..31
  const int sun = t & 7;
  const int u8 = (sun ^ (srow & 7)) << 3;
  const __hip_bfloat16* sA = A + (size_t)(tm0 + srow) * K + u8;
  const __hip_bfloat16* sA2 = sA + (size_t)64 * K;

  const char* bpB = (const char*)(Wp + (size_t)((tn0 >> 6) + wc) * NKT * 4096) +
                    l * 16;

  // A fragment-read bases (unit-XOR swizzle; r&7 == lrow&7 for all frags)
  const int lo = lrow * 128;
  const int x0 = (lhi ^ (lrow & 7)) << 4;
  const int x1 = ((4 + lhi) ^ (lrow & 7)) << 4;
  const char* pbase = lds + wr * 8192 + lo;  // + p*32768 + sub*16384 (+x,m)

  // stage 2 K-tiles (128 k) of the 128-row A panel into buf p (8 gloads)
  auto stage = [&](int p, int ktb) {
    char* base = lds + p * 32768 + w * 1024;
#pragma unroll
    for (int sub = 0; sub < 2; ++sub) {
      const int kt = ktb + sub;
      char* d = base + sub * 16384;
      const __hip_bfloat16* s0 = sA + kt * 64;
      gload_lds16(s0, d);
      gload_lds16(s0 + (size_t)32 * K, d + 4096);
      const __hip_bfloat16* s1 = sA2 + kt * 64;
      gload_lds16(s1, d + 8192);
      gload_lds16(s1 + (size_t)32 * K, d + 12288);
    }
  };

  f32x4 acc[4][4] = {};
  bf16x8 af[4][2], bf[2][2];

  // ---- prologue: K-tiles 0,1 into buf0
  stage(0, 0);
  asm volatile("s_waitcnt vmcnt(0)" ::: "memory");
  __builtin_amdgcn_sched_barrier(0);
  __builtin_amdgcn_s_barrier();

  for (int ph = 0; ph < NP; ++ph) {
    const int p = ph & 1;
    const int ktb = 2 * ph;
    const bool more = (ph + 1 < NP);
    if (more) stage(p ^ 1, ktb + 2);
    __builtin_amdgcn_sched_barrier(0);
#pragma unroll
    for (int sub = 0; sub < 2; ++sub) {
      const char* ab = pbase + p * 32768 + sub * 16384;
#pragma unroll
      for (int m = 0; m < 4; ++m) {
        af[m][0] = *(const bf16x8*)(ab + x0 + m * 2048);
        af[m][1] = *(const bf16x8*)(ab + x1 + m * 2048);
      }
      const char* qb = bpB + (size_t)(ktb + sub) * 8192;
#pragma unroll
      for (int np = 0; np < 2; ++np) {
#pragma unroll
        for (int n = 0; n < 2; ++n)
#pragma unroll
          for (int ks = 0; ks < 2; ++ks)
            bf[n][ks] =
                *(const bf16x8*)(qb + ((np * 2 + n) * 2 + ks) * 1024);
#pragma unroll
        for (int m = 0; m < 4; ++m)
#pragma unroll
          for (int n = 0; n < 2; ++n)
#pragma unroll
            for (int ks = 0; ks < 2; ++ks)
              acc[m][np * 2 + n] = __builtin_amdgcn_mfma_f32_16x16x32_bf16(
                  af[m][ks], bf[n][ks], acc[m][np * 2 + n], 0, 0, 0);
      }
    }
    if (more) asm volatile("s_waitcnt vmcnt(16)" ::: "memory");
    asm volatile("s_waitcnt lgkmcnt(0)" ::: "memory");
    __builtin_amdgcn_sched_barrier(0);
    __builtin_amdgcn_s_barrier();
  }

  // ---- epilogue: wave-private LDS transpose (unit-XOR swizzled), uint4 stores
  char* ep = lds + w * 8192;  // 64x64 bf16, row stride 128B
#pragma unroll
  for (int n = 0; n < 4; ++n) {
    float bv = bias[tn0 + wc * 64 + n * 16 + lrow];
#pragma unroll
    for (int m = 0; m < 4; ++m)
#pragma unroll
      for (int j = 0; j < 4; ++j) {
        float v = acc[m][n][j] + bv;
        if (RELU) v = fmaxf(v, 0.f);
        int row = m * 16 + lhi * 4 + j;
        int col = n * 16 + lrow;
        *(__hip_bfloat16*)(ep + row * 128 + (((col >> 3) ^ (row & 7)) << 4) +
                           (col & 7) * 2) = __float2bfloat16(v);
      }
  }
  __builtin_amdgcn_sched_barrier(0);
  const int er = l >> 3, ec = l & 7;
#pragma unroll
  for (int q = 0; q < 8; ++q) {
    int r = q * 8 + er;
    uint4 vv = *(const uint4*)(ep + r * 128 + ((ec ^ (r & 7)) << 4));
    *(uint4*)&Cout[(size_t)(tm0 + wr * 64 + r) * N + tn0 + wc * 64 + ec * 8] = vv;
  }
}

// ---------------- Windowed attention: one wave per (window, b, h) --------
__global__ __launch_bounds__(128) void attn_win(
    const __hip_bfloat16* __restrict__ qkv, __hip_bfloat16* __restrict__ o) {
  __shared__ __align__(16) char lds[2 * 18432];
  const int t = threadIdx.x, l = t & 63, w = t >> 6;
  char* vt = lds + w * 18432;          // Vt[d][k], stride 72 bf16
  char* pl = vt + 9216;                // P[q][k],  stride 72 bf16
  const int wid = blockIdx.x * 2 + w;
  const int h = wid & 7, b = (wid >> 3) & 3, nw = wid >> 5;
  const int lrow = l & 15, lhi = l >> 4;
  const __hip_bfloat16* qp = qkv + (size_t)(nw * 256 + b) * 1536 + h * 64;
  const __hip_bfloat16* kp = qp + 512;
  const __hip_bfloat16* vp = qp + 1024;

  {
    const int d0 = (l & 7) * 8;
    const int r0 = l >> 3;
#pragma unroll
    for (int i = 0; i < 8; ++i) {
      int r = r0 + i * 8;
      union { uint4 u; __hip_bfloat16 e[8]; } vv;
      vv.u = *(const uint4*)(vp + (size_t)r * 6144 + d0);
#pragma unroll
      for (int j = 0; j < 8; ++j)
        *(__hip_bfloat16*)(vt + ((d0 + j) * 72 + r) * 2) = vv.e[j];
    }
  }

  bf16x8 qf[4][2], kf[4][2];
#pragma unroll
  for (int mi = 0; mi < 4; ++mi)
#pragma unroll
    for (int ks = 0; ks < 2; ++ks) {
      int r = mi * 16 + lrow;
      int d = ks * 32 + lhi * 8;
      qf[mi][ks] = __builtin_bit_cast(bf16x8, *(const uint4*)(qp + (size_t)r * 6144 + d));
      kf[mi][ks] = __builtin_bit_cast(bf16x8, *(const uint4*)(kp + (size_t)r * 6144 + d));
    }

  f32x4 s[4][4] = {};
#pragma unroll
  for (int mi = 0; mi < 4; ++mi)
#pragma unroll
    for (int ni = 0; ni < 4; ++ni) {
      s[mi][ni] = __builtin_amdgcn_mfma_f32_16x16x32_bf16(qf[mi][0], kf[ni][0], s[mi][ni], 0, 0, 0);
      s[mi][ni] = __builtin_amdgcn_mfma_f32_16x16x32_bf16(qf[mi][1], kf[ni][1], s[mi][ni], 0, 0, 0);
    }

#pragma unroll
  for (int mi = 0; mi < 4; ++mi)
#pragma unroll
    for (int j = 0; j < 4; ++j) {
      float mx = s[mi][0][j];
#pragma unroll
      for (int ni = 1; ni < 4; ++ni) mx = fmaxf(mx, s[mi][ni][j]);
      mx = fmaxf(mx, __shfl_xor(mx, 1));
      mx = fmaxf(mx, __shfl_xor(mx, 2));
      mx = fmaxf(mx, __shfl_xor(mx, 4));
      mx = fmaxf(mx, __shfl_xor(mx, 8));
      float p[4], sum = 0.f;
#pragma unroll
      for (int ni = 0; ni < 4; ++ni) { p[ni] = __expf(s[mi][ni][j] - mx); sum += p[ni]; }
      sum += __shfl_xor(sum, 1);
      sum += __shfl_xor(sum, 2);
      sum += __shfl_xor(sum, 4);
      sum += __shfl_xor(sum, 8);
      float inv = 1.f / sum;
      int row = mi * 16 + lhi * 4 + j;
#pragma unroll
      for (int ni = 0; ni < 4; ++ni)
        *(__hip_bfloat16*)(pl + (row * 72 + ni * 16 + lrow) * 2) =
            __float2bfloat16(p[ni] * inv);
    }

  bf16x8 pf[4][2], vf[4][2];
#pragma unroll
  for (int mi = 0; mi < 4; ++mi)
#pragma unroll
    for (int ks = 0; ks < 2; ++ks)
      pf[mi][ks] = *(const bf16x8*)(pl + ((mi * 16 + lrow) * 72 + ks * 32 + lhi * 8) * 2);
#pragma unroll
  for (int ni = 0; ni < 4; ++ni)
#pragma unroll
    for (int ks = 0; ks < 2; ++ks)
      vf[ni][ks] = *(const bf16x8*)(vt + ((ni * 16 + lrow) * 72 + ks * 32 + lhi * 8) * 2);

  f32x4 acc[4][4] = {};
#pragma unroll
  for (int mi = 0; mi < 4; ++mi)
#pragma unroll
    for (int ni = 0; ni < 4; ++ni) {
      acc[mi][ni] = __builtin_amdgcn_mfma_f32_16x16x32_bf16(pf[mi][0], vf[ni][0], acc[mi][ni], 0, 0, 0);
      acc[mi][ni] = __builtin_amdgcn_mfma_f32_16x16x32_bf16(pf[mi][1], vf[ni][1], acc[mi][ni], 0, 0, 0);
    }

  __hip_bfloat16* op = o + (size_t)(nw * 256 + b) * 512 + h * 64;
#pragma unroll
  for (int mi = 0; mi < 4; ++mi)
#pragma unroll
    for (int ni = 0; ni < 4; ++ni) {
      int col = ni * 16 + lrow;
#pragma unroll
      for (int j = 0; j < 4; ++j) {
        int row = mi * 16 + lhi * 4 + j;
        op[(size_t)row * 2048 + col] = __float2bfloat16(acc[mi][ni][j]);
      }
    }
}

// -------- residual + LayerNorm on bf16 master (wave per row of 512) -------
template<bool LAST>
__global__ __launch_bounds__(256) void ln_res_b(
    __hip_bfloat16* __restrict__ xb, const __hip_bfloat16* __restrict__ f,
    const float* __restrict__ g, const float* __restrict__ be,
    float* __restrict__ xout) {
  const int w = threadIdx.x >> 6, l = threadIdx.x & 63;
  const size_t row = (size_t)blockIdx.x * 4 + w;
  const int c = l * 8;
  union { uint4 u; __hip_bfloat16 e[8]; } xa, fa;
  xa.u = *(const uint4*)(xb + row * 512 + c);
  fa.u = *(const uint4*)(f + row * 512 + c);
  float v[8];
#pragma unroll
  for (int j = 0; j < 8; ++j)
    v[j] = __bfloat162float(xa.e[j]) + __bfloat162float(fa.e[j]);
  float sum = 0.f, sq = 0.f;
#pragma unroll
  for (int j = 0; j < 8; ++j) { sum += v[j]; sq += v[j] * v[j]; }
#pragma unroll
  for (int m = 1; m < 64; m <<= 1) {
    sum += __shfl_xor(sum, m);
    sq += __shfl_xor(sq, m);
  }
  float mean = sum * (1.f / 512.f);
  float var = sq * (1.f / 512.f) - mean * mean;
  float rs = rsqrtf(var + 1e-5f);
  float4 g0 = *(const float4*)(g + c);
  float4 g1v = *(const float4*)(g + c + 4);
  float4 e0 = *(const float4*)(be + c);
  float4 e1 = *(const float4*)(be + c + 4);
  float gg[8] = {g0.x, g0.y, g0.z, g0.w, g1v.x, g1v.y, g1v.z, g1v.w};
  float ee[8] = {e0.x, e0.y, e0.z, e0.w, e1.x, e1.y, e1.z, e1.w};
  float y[8];
  union { uint4 u; __hip_bfloat16 e[8]; } hb;
#pragma unroll
  for (int j = 0; j < 8; ++j) {
    y[j] = (v[j] - mean) * rs * gg[j] + ee[j];
    hb.e[j] = __float2bfloat16(y[j]);
  }
  *(uint4*)(xb + row * 512 + c) = hb.u;
  if (LAST) {
    float4 o0 = {y[0], y[1], y[2], y[3]};
    float4 o1 = {y[4], y[5], y[6], y[7]};
    *(float4*)(xout + row * 512 + c) = o0;
    *(float4*)(xout + row * 512 + c + 4) = o1;
  }
}

// ---------------- setup / conversion kernels ------------------------------
__global__ void convw(const float* __restrict__ s, __hip_bfloat16* __restrict__ o) {
  int i = blockIdx.x * 256 + threadIdx.x;  // exact grids only
  float4 v = ((const float4*)s)[i];
  __hip_bfloat16 hb[4] = {__float2bfloat16(v.x), __float2bfloat16(v.y),
                          __float2bfloat16(v.z), __float2bfloat16(v.w)};
  ((uint2*)o)[i] = *(uint2*)hb;
}

// fp32 [L][Nw][K] -> bf16 fragment-major swizzled layout (see gemm2).
template<int K, int Nw, bool SCALEQ>
__global__ void convs(const float* __restrict__ s, __hip_bfloat16* __restrict__ o) {
  int i = blockIdx.x * 256 + threadIdx.x;  // over L*Nw*K/4 exactly
  int e = i * 4;
  int layer = e / (Nw * K);
  int rem = e - layer * (Nw * K);
  int r = rem / K, c = rem - r * K;
  float4 v = ((const float4*)s)[i];
  float sc = (SCALEQ && r < 512) ? 0.125f : 1.f;
  int didx = layer * (Nw * K) + ((r >> 6) * (K >> 6) + (c >> 6)) * 4096 +
             (((r >> 4) & 3) * 2 + ((c >> 5) & 1)) * 512 + ((c >> 3) & 3) * 128 +
             (r & 15) * 8 + (c & 7);
  __hip_bfloat16 hb[4] = {__float2bfloat16(v.x * sc), __float2bfloat16(v.y * sc),
                          __float2bfloat16(v.z * sc), __float2bfloat16(v.w * sc)};
  *(uint2*)(o + didx) = *(uint2*)hb;
}

__global__ void scaleb(const float* __restrict__ b, float* __restrict__ o) {
  int i = blockIdx.x * 256 + threadIdx.x;  // over 9216 exactly
  o[i] = b[i] * (((i % 1536) < 512) ? 0.125f : 1.f);
}

// ---------------- launch ---------------------------------------------------
extern "C" void kernel_launch(void* const* d_in, const int* in_sizes, int n_in,
                              void* d_out, int out_size, void* d_ws, size_t ws_size,
                              hipStream_t stream) {
  const float* src  = (const float*)d_in[0];
  const float* Wqkv = (const float*)d_in[1];
  const float* bqkv = (const float*)d_in[2];
  const float* Wo   = (const float*)d_in[3];
  const float* bo   = (const float*)d_in[4];
  const float* W1   = (const float*)d_in[5];
  const float* bf1  = (const float*)d_in[6];
  const float* W2   = (const float*)d_in[7];
  const float* bf2  = (const float*)d_in[8];
  const float* g1   = (const float*)d_in[9];
  const float* be1  = (const float*)d_in[10];
  const float* g2   = (const float*)d_in[11];
  const float* be2  = (const float*)d_in[12];
  float* xout = (float*)d_out;  // fp32 output, written by the final LN

  char* ws = (char*)d_ws;
  size_t off = 0;
  auto alloc = [&](size_t bytes) {
    char* p = ws + off;
    off += (bytes + 255) & ~(size_t)255;
    return p;
  };

  const size_t wq_b = (size_t)L_ * D3 * D_ * 2;
  const size_t wo_b = (size_t)L_ * D_ * D_ * 2;
  const size_t w1_b = (size_t)L_ * DF * D_ * 2;
  const size_t w2_b = (size_t)L_ * D_ * DF * 2;
  const size_t xb_b = (size_t)NT * 512 * 2;  // bf16 residual master
  auto al = [](size_t v) { return (v + 255) & ~(size_t)255; };
  const size_t persist =
      al(wq_b) + al(wo_b) + al(w1_b) + al(w2_b) + al(L_ * D3 * 4) + al(xb_b);

  int CT = NT;
  while (CT > 2048 && persist + (size_t)CT * 5120 + 65536 > ws_size) CT >>= 1;

  __hip_bfloat16* wqkvb = (__hip_bfloat16*)alloc(wq_b);
  __hip_bfloat16* wob   = (__hip_bfloat16*)alloc(wo_b);
  __hip_bfloat16* w1b   = (__hip_bfloat16*)alloc(w1_b);
  __hip_bfloat16* w2b   = (__hip_bfloat16*)alloc(w2_b);
  float*          bqs   = (float*)alloc((size_t)L_ * D3 * 4);
  __hip_bfloat16* xb    = (__hip_bfloat16*)alloc(xb_b);
  __hip_bfloat16* R     = (__hip_bfloat16*)alloc((size_t)CT * 2048 * 2);
  __hip_bfloat16* OB    = (__hip_bfloat16*)alloc((size_t)CT * 512 * 2);

  convw<<<NT * 512 / 4 / 256, 256, 0, stream>>>(src, xb);
  convs<512, 1536, true><<<L_ * D3 * D_ / 4 / 256, 256, 0, stream>>>(Wqkv, wqkvb);
  convs<512, 512, false><<<L_ * D_ * D_ / 4 / 256, 256, 0, stream>>>(Wo, wob);
  convs<512, 2048, false><<<L_ * DF * D_ / 4 / 256, 256, 0, stream>>>(W1, w1b);
  convs<2048, 512, false><<<L_ * D_ * DF / 4 / 256, 256, 0, stream>>>(W2, w2b);
  scaleb<<<L_ * D3 / 256, 256, 0, stream>>>(bqkv, bqs);

  const int nch = NT / CT;
  for (int c = 0; c < nch; ++c) {
    __hip_bfloat16* xm = xb + (size_t)c * CT * 512;
    float* xo = xout + (size_t)c * CT * 512;
    for (int l = 0; l < L_; ++l) {
      // qkv -> R[0 .. CT*1536): 12 x 128-col tiles
      gemm2<512, 12, false><<<(CT / 128) * 12, 256, 0, stream>>>(
          xm, wqkvb + (size_t)l * D3 * D_, bqs + l * D3, R);
      attn_win<<<CT / 16, 128, 0, stream>>>(R, OB);
      // o-proj -> R[0 .. CT*512): 4 tiles
      gemm2<512, 4, false><<<(CT / 128) * 4, 256, 0, stream>>>(
          OB, wob + (size_t)l * D_ * D_, bo + l * D_, R);
      ln_res_b<false><<<CT / 4, 256, 0, stream>>>(xm, R, g1 + l * D_,
                                                  be1 + l * D_, xo);
      // ffn1 -> R full: 16 tiles
      gemm2<512, 16, true><<<(CT / 128) * 16, 256, 0, stream>>>(
          xm, w1b + (size_t)l * DF * D_, bf1 + l * DF, R);
      // ffn2 -> OB: 4 tiles
      gemm2<2048, 4, false><<<(CT / 128) * 4, 256, 0, stream>>>(
          R, w2b + (size_t)l * D_ * DF, bf2 + l * D_, OB);
      if (l == L_ - 1)
        ln_res_b<true><<<CT / 4, 256, 0, stream>>>(xm, OB, g2 + l * D_,
                                                   be2 + l * D_, xo);
      else
        ln_res_b<false><<<CT / 4, 256, 0, stream>>>(xm, OB, g2 + l * D_,
                                                    be2 + l * D_, xo);
    }
  }
}

// Round 17
// 1810.513 us; speedup vs baseline: 1.1902x; 1.1902x over previous
//
#include <hip/hip_runtime.h>
#include <hip/hip_bf16.h>

typedef __bf16 bf16x8 __attribute__((ext_vector_type(8)));
typedef float f32x4 __attribute__((ext_vector_type(4)));

static constexpr int NT = 32768;  // S*B tokens
static constexpr int D_ = 512;
static constexpr int D3 = 1536;
static constexpr int DF = 2048;
static constexpr int L_ = 6;

#define AS1 __attribute__((address_space(1)))
#define AS3 __attribute__((address_space(3)))

__device__ __forceinline__ void gload_lds16(const void* g, void* l) {
  __builtin_amdgcn_global_load_lds((const AS1 void*)g, (AS3 void*)l, 16, 0, 0);
}

// ===== 128x128 GEMM (round-11 structure): A via LDS dbuf, B from global ====
// 4 waves (2M x 2N), per-wave 64x64. 32 KB LDS; launch_bounds(256,3).
// One phase per K-tile, one barrier per phase; B double-buffered in regs
// ACROSS phases (bfA/bfB), staged A one phase ahead. Ledger (verified r11):
//   phase k0: stageA(buf1, k1); loadB(bfB, k1); MFMA(buf0, bfA);
//             close: vmcnt(8) lgkm(0) barrier
//   phase k1: [more] stageA(buf0, k2); loadB(bfA, k2); MFMA(buf1, bfB);
//             close: vmcnt(8|0) lgkm(0) barrier
// vmcnt(8) drains exactly the 4 stage gloads (issued before the 8 B-loads;
// in-order retire) -> next phase's ds_reads are RAW-safe. WAR: each wave's
// ds_reads drain at its lgkmcnt(0) before the barrier; re-stage is next
// phase. THIS REVISION (r17): induction pointers (sAe/qbe advanced by
// constant strides) + split B base so all B offsets fit the 13-bit global
// immediate -- fewer per-phase VALU address ops; schedule unchanged.
// B' layout (convs<>, verified r11): row r, col c of an N x K weight:
//   ((r>>6)*(K>>6)+(c>>6))*4096 + (((r>>4)&3)*2+((c>>5)&1))*512
//   + ((c>>3)&3)*128 + (r&15)*8 + (c&7)   [ELEMENT offsets]
template<int K, int NTN, bool RELU>
__global__ __launch_bounds__(256, 3) void gemm128g(
    const __hip_bfloat16* __restrict__ A,
    const __hip_bfloat16* __restrict__ Wp,
    const float* __restrict__ bias,
    __hip_bfloat16* __restrict__ Cout) {
  __shared__ __align__(16) char lds[32768];
  const int t = threadIdx.x;
  const int l = t & 63, w = t >> 6;       // 4 waves
  const int lrow = l & 15, lhi = l >> 4;
  const int wr = w >> 1, wc = w & 1;      // 2M x 2N

  const int lin = blockIdx.x;
  const int wg = (lin & 7) * ((int)gridDim.x >> 3) + (lin >> 3);
  const int tm0 = (wg / NTN) * 128, tn0 = (wg % NTN) * 128;

  constexpr int NKT = K / 64;
  constexpr int NIT = NKT / 2;
  constexpr int N = NTN * 128;

  const int srow = t >> 3;  // 0..31
  const int sun = t & 7;
  const int u8 = (sun ^ (srow & 7)) << 3;
  const __hip_bfloat16* sA = A + (size_t)(tm0 + srow) * K + u8;
  const __hip_bfloat16* sA2 = sA + (size_t)64 * K;

  const char* bpB = (const char*)(Wp + (size_t)((tn0 >> 6) + wc) * NKT * 4096) +
                    l * 16;

  // A fragment-read bases (unit-XOR swizzle; r&7 == lrow&7 for all frags)
  const int lo = lrow * 128;
  const int x0 = (lhi ^ (lrow & 7)) << 4;
  const int x1 = ((4 + lhi) ^ (lrow & 7)) << 4;
  const char* pA[2][2];
  pA[0][0] = lds + wr * 8192 + lo + x0;
  pA[0][1] = lds + wr * 8192 + lo + x1;
  pA[1][0] = lds + 16384 + wr * 8192 + lo + x0;
  pA[1][1] = lds + 16384 + wr * 8192 + lo + x1;

  // stage one K-tile of the A panel into buf p (4 gloads); s0/s1 = row 0/64
  auto stageA = [&](int p, const __hip_bfloat16* s0, const __hip_bfloat16* s1) {
    char* d0 = lds + p * 16384 + w * 1024;
    gload_lds16(s0, d0);
    gload_lds16(s0 + (size_t)32 * K, d0 + 4096);
    char* d1 = lds + p * 16384 + 8192 + w * 1024;
    gload_lds16(s1, d1);
    gload_lds16(s1 + (size_t)32 * K, d1 + 4096);
  };
  auto loadB = [&](bf16x8 (&bf)[4][2], const char* q) {
    const char* q2 = q + 4096;
#pragma unroll
    for (int n = 0; n < 2; ++n)
#pragma unroll
      for (int ks = 0; ks < 2; ++ks) {
        bf[n][ks] = *(const bf16x8*)(q + (n * 2 + ks) * 1024);
        bf[2 + n][ks] = *(const bf16x8*)(q2 + (n * 2 + ks) * 1024);
      }
  };

  f32x4 acc[4][4] = {};
  bf16x8 bfA[4][2], bfB[4][2], af[2][2];

  // ---- prologue: tile 0 -> buf0 + bfA
  stageA(0, sA, sA2);
  __builtin_amdgcn_sched_barrier(0);
  loadB(bfA, bpB);
  asm volatile("s_waitcnt vmcnt(8)" ::: "memory");
  __builtin_amdgcn_sched_barrier(0);
  __builtin_amdgcn_s_barrier();

#define SUB(P, BF, MB)                                                      \
  {                                                                          \
    _Pragma("unroll") for (int ks = 0; ks < 2; ++ks) {                       \
      af[0][ks] = *(const bf16x8*)(pA[P][ks] + (MB) * 2048);                 \
      af[1][ks] = *(const bf16x8*)(pA[P][ks] + (MB + 1) * 2048);             \
    }                                                                        \
    _Pragma("unroll") for (int n = 0; n < 4; ++n)                            \
        _Pragma("unroll") for (int ks = 0; ks < 2; ++ks) {                   \
      acc[MB][n] = __builtin_amdgcn_mfma_f32_16x16x32_bf16(                  \
          af[0][ks], BF[n][ks], acc[MB][n], 0, 0, 0);                        \
      acc[MB + 1][n] = __builtin_amdgcn_mfma_f32_16x16x32_bf16(              \
          af[1][ks], BF[n][ks], acc[MB + 1][n], 0, 0, 0);                    \
    }                                                                        \
  }
#define CLOSE(VM)                                                           \
  if (VM) asm volatile("s_waitcnt vmcnt(8)" ::: "memory");                  \
  else asm volatile("s_waitcnt vmcnt(0)" ::: "memory");                     \
  asm volatile("s_waitcnt lgkmcnt(0)" ::: "memory");                        \
  __builtin_amdgcn_sched_barrier(0);                                        \
  __builtin_amdgcn_s_barrier();

  const __hip_bfloat16* sAe = sA;    // A row-0 base at current even tile
  const __hip_bfloat16* sA2e = sA2;  // A row-64 base at current even tile
  const char* qbe = bpB;             // B base (bytes) at current even tile
  for (int it = 0; it < NIT; ++it) {
    const bool more = (it + 1 < NIT);
    // phase k0: A from buf0, B = bfA
    stageA(1, sAe + 64, sA2e + 64);
    __builtin_amdgcn_sched_barrier(0);
    loadB(bfB, qbe + 8192);
    SUB(0, bfA, 0)
    SUB(0, bfA, 2)
    CLOSE(1)
    // phase k1: A from buf1, B = bfB
    if (more) {
      stageA(0, sAe + 128, sA2e + 128);
      __builtin_amdgcn_sched_barrier(0);
      loadB(bfA, qbe + 16384);
    }
    SUB(1, bfB, 0)
    SUB(1, bfB, 2)
    CLOSE(more)
    sAe += 128;
    sA2e += 128;
    qbe += 16384;
  }
#undef SUB
#undef CLOSE

  // ---- epilogue: wave-private LDS transpose (unit-XOR swizzled), uint4 stores
  char* ep = lds + w * 8192;  // 64x64 bf16, row stride 128B
#pragma unroll
  for (int n = 0; n < 4; ++n) {
    float bv = bias[tn0 + wc * 64 + n * 16 + lrow];
#pragma unroll
    for (int m = 0; m < 4; ++m)
#pragma unroll
      for (int j = 0; j < 4; ++j) {
        float v = acc[m][n][j] + bv;
        if (RELU) v = fmaxf(v, 0.f);
        int row = m * 16 + lhi * 4 + j;
        int col = n * 16 + lrow;
        *(__hip_bfloat16*)(ep + row * 128 + (((col >> 3) ^ (row & 7)) << 4) +
                           (col & 7) * 2) = __float2bfloat16(v);
      }
  }
  __builtin_amdgcn_sched_barrier(0);
  const int er = l >> 3, ec = l & 7;
#pragma unroll
  for (int q = 0; q < 8; ++q) {
    int r = q * 8 + er;
    uint4 vv = *(const uint4*)(ep + r * 128 + ((ec ^ (r & 7)) << 4));
    *(uint4*)&Cout[(size_t)(tm0 + wr * 64 + r) * N + tn0 + wc * 64 + ec * 8] = vv;
  }
}

// ---------------- Windowed attention: one wave per (window, b, h) --------
__global__ __launch_bounds__(128) void attn_win(
    const __hip_bfloat16* __restrict__ qkv, __hip_bfloat16* __restrict__ o) {
  __shared__ __align__(16) char lds[2 * 18432];
  const int t = threadIdx.x, l = t & 63, w = t >> 6;
  char* vt = lds + w * 18432;          // Vt[d][k], stride 72 bf16
  char* pl = vt + 9216;                // P[q][k],  stride 72 bf16
  const int wid = blockIdx.x * 2 + w;
  const int h = wid & 7, b = (wid >> 3) & 3, nw = wid >> 5;
  const int lrow = l & 15, lhi = l >> 4;
  const __hip_bfloat16* qp = qkv + (size_t)(nw * 256 + b) * 1536 + h * 64;
  const __hip_bfloat16* kp = qp + 512;
  const __hip_bfloat16* vp = qp + 1024;

  {
    const int d0 = (l & 7) * 8;
    const int r0 = l >> 3;
#pragma unroll
    for (int i = 0; i < 8; ++i) {
      int r = r0 + i * 8;
      union { uint4 u; __hip_bfloat16 e[8]; } vv;
      vv.u = *(const uint4*)(vp + (size_t)r * 6144 + d0);
#pragma unroll
      for (int j = 0; j < 8; ++j)
        *(__hip_bfloat16*)(vt + ((d0 + j) * 72 + r) * 2) = vv.e[j];
    }
  }

  bf16x8 qf[4][2], kf[4][2];
#pragma unroll
  for (int mi = 0; mi < 4; ++mi)
#pragma unroll
    for (int ks = 0; ks < 2; ++ks) {
      int r = mi * 16 + lrow;
      int d = ks * 32 + lhi * 8;
      qf[mi][ks] = __builtin_bit_cast(bf16x8, *(const uint4*)(qp + (size_t)r * 6144 + d));
      kf[mi][ks] = __builtin_bit_cast(bf16x8, *(const uint4*)(kp + (size_t)r * 6144 + d));
    }

  f32x4 s[4][4] = {};
#pragma unroll
  for (int mi = 0; mi < 4; ++mi)
#pragma unroll
    for (int ni = 0; ni < 4; ++ni) {
      s[mi][ni] = __builtin_amdgcn_mfma_f32_16x16x32_bf16(qf[mi][0], kf[ni][0], s[mi][ni], 0, 0, 0);
      s[mi][ni] = __builtin_amdgcn_mfma_f32_16x16x32_bf16(qf[mi][1], kf[ni][1], s[mi][ni], 0, 0, 0);
    }

#pragma unroll
  for (int mi = 0; mi < 4; ++mi)
#pragma unroll
    for (int j = 0; j < 4; ++j) {
      float mx = s[mi][0][j];
#pragma unroll
      for (int ni = 1; ni < 4; ++ni) mx = fmaxf(mx, s[mi][ni][j]);
      mx = fmaxf(mx, __shfl_xor(mx, 1));
      mx = fmaxf(mx, __shfl_xor(mx, 2));
      mx = fmaxf(mx, __shfl_xor(mx, 4));
      mx = fmaxf(mx, __shfl_xor(mx, 8));
      float p[4], sum = 0.f;
#pragma unroll
      for (int ni = 0; ni < 4; ++ni) { p[ni] = __expf(s[mi][ni][j] - mx); sum += p[ni]; }
      sum += __shfl_xor(sum, 1);
      sum += __shfl_xor(sum, 2);
      sum += __shfl_xor(sum, 4);
      sum += __shfl_xor(sum, 8);
      float inv = 1.f / sum;
      int row = mi * 16 + lhi * 4 + j;
#pragma unroll
      for (int ni = 0; ni < 4; ++ni)
        *(__hip_bfloat16*)(pl + (row * 72 + ni * 16 + lrow) * 2) =
            __float2bfloat16(p[ni] * inv);
    }

  bf16x8 pf[4][2], vf[4][2];
#pragma unroll
  for (int mi = 0; mi < 4; ++mi)
#pragma unroll
    for (int ks = 0; ks < 2; ++ks)
      pf[mi][ks] = *(const bf16x8*)(pl + ((mi * 16 + lrow) * 72 + ks * 32 + lhi * 8) * 2);
#pragma unroll
  for (int ni = 0; ni < 4; ++ni)
#pragma unroll
    for (int ks = 0; ks < 2; ++ks)
      vf[ni][ks] = *(const bf16x8*)(vt + ((ni * 16 + lrow) * 72 + ks * 32 + lhi * 8) * 2);

  f32x4 acc[4][4] = {};
#pragma unroll
  for (int mi = 0; mi < 4; ++mi)
#pragma unroll
    for (int ni = 0; ni < 4; ++ni) {
      acc[mi][ni] = __builtin_amdgcn_mfma_f32_16x16x32_bf16(pf[mi][0], vf[ni][0], acc[mi][ni], 0, 0, 0);
      acc[mi][ni] = __builtin_amdgcn_mfma_f32_16x16x32_bf16(pf[mi][1], vf[ni][1], acc[mi][ni], 0, 0, 0);
    }

  __hip_bfloat16* op = o + (size_t)(nw * 256 + b) * 512 + h * 64;
#pragma unroll
  for (int mi = 0; mi < 4; ++mi)
#pragma unroll
    for (int ni = 0; ni < 4; ++ni) {
      int col = ni * 16 + lrow;
#pragma unroll
      for (int j = 0; j < 4; ++j) {
        int row = mi * 16 + lhi * 4 + j;
        op[(size_t)row * 2048 + col] = __float2bfloat16(acc[mi][ni][j]);
      }
    }
}

// -------- residual + LayerNorm on bf16 master (wave per row of 512) -------
template<bool LAST>
__global__ __launch_bounds__(256) void ln_res_b(
    __hip_bfloat16* __restrict__ xb, const __hip_bfloat16* __restrict__ f,
    const float* __restrict__ g, const float* __restrict__ be,
    float* __restrict__ xout) {
  const int w = threadIdx.x >> 6, l = threadIdx.x & 63;
  const size_t row = (size_t)blockIdx.x * 4 + w;
  const int c = l * 8;
  union { uint4 u; __hip_bfloat16 e[8]; } xa, fa;
  xa.u = *(const uint4*)(xb + row * 512 + c);
  fa.u = *(const uint4*)(f + row * 512 + c);
  float v[8];
#pragma unroll
  for (int j = 0; j < 8; ++j)
    v[j] = __bfloat162float(xa.e[j]) + __bfloat162float(fa.e[j]);
  float sum = 0.f, sq = 0.f;
#pragma unroll
  for (int j = 0; j < 8; ++j) { sum += v[j]; sq += v[j] * v[j]; }
#pragma unroll
  for (int m = 1; m < 64; m <<= 1) {
    sum += __shfl_xor(sum, m);
    sq += __shfl_xor(sq, m);
  }
  float mean = sum * (1.f / 512.f);
  float var = sq * (1.f / 512.f) - mean * mean;
  float rs = rsqrtf(var + 1e-5f);
  float4 g0 = *(const float4*)(g + c);
  float4 g1v = *(const float4*)(g + c + 4);
  float4 e0 = *(const float4*)(be + c);
  float4 e1 = *(const float4*)(be + c + 4);
  float gg[8] = {g0.x, g0.y, g0.z, g0.w, g1v.x, g1v.y, g1v.z, g1v.w};
  float ee[8] = {e0.x, e0.y, e0.z, e0.w, e1.x, e1.y, e1.z, e1.w};
  float y[8];
  union { uint4 u; __hip_bfloat16 e[8]; } hb;
#pragma unroll
  for (int j = 0; j < 8; ++j) {
    y[j] = (v[j] - mean) * rs * gg[j] + ee[j];
    hb.e[j] = __float2bfloat16(y[j]);
  }
  *(uint4*)(xb + row * 512 + c) = hb.u;
  if (LAST) {
    float4 o0 = {y[0], y[1], y[2], y[3]};
    float4 o1 = {y[4], y[5], y[6], y[7]};
    *(float4*)(xout + row * 512 + c) = o0;
    *(float4*)(xout + row * 512 + c + 4) = o1;
  }
}

// ---------------- setup / conversion kernels ------------------------------
__global__ void convw(const float* __restrict__ s, __hip_bfloat16* __restrict__ o) {
  int i = blockIdx.x * 256 + threadIdx.x;  // exact grids only
  float4 v = ((const float4*)s)[i];
  __hip_bfloat16 hb[4] = {__float2bfloat16(v.x), __float2bfloat16(v.y),
                          __float2bfloat16(v.z), __float2bfloat16(v.w)};
  ((uint2*)o)[i] = *(uint2*)hb;
}

// fp32 [L][Nw][K] -> bf16 fragment-major swizzled layout (see gemm128g).
template<int K, int Nw, bool SCALEQ>
__global__ void convs(const float* __restrict__ s, __hip_bfloat16* __restrict__ o) {
  int i = blockIdx.x * 256 + threadIdx.x;  // over L*Nw*K/4 exactly
  int e = i * 4;
  int layer = e / (Nw * K);
  int rem = e - layer * (Nw * K);
  int r = rem / K, c = rem - r * K;
  float4 v = ((const float4*)s)[i];
  float sc = (SCALEQ && r < 512) ? 0.125f : 1.f;
  int didx = layer * (Nw * K) + ((r >> 6) * (K >> 6) + (c >> 6)) * 4096 +
             (((r >> 4) & 3) * 2 + ((c >> 5) & 1)) * 512 + ((c >> 3) & 3) * 128 +
             (r & 15) * 8 + (c & 7);
  __hip_bfloat16 hb[4] = {__float2bfloat16(v.x * sc), __float2bfloat16(v.y * sc),
                          __float2bfloat16(v.z * sc), __float2bfloat16(v.w * sc)};
  *(uint2*)(o + didx) = *(uint2*)hb;
}

__global__ void scaleb(const float* __restrict__ b, float* __restrict__ o) {
  int i = blockIdx.x * 256 + threadIdx.x;  // over 9216 exactly
  o[i] = b[i] * (((i % 1536) < 512) ? 0.125f : 1.f);
}

// ---------------- launch ---------------------------------------------------
extern "C" void kernel_launch(void* const* d_in, const int* in_sizes, int n_in,
                              void* d_out, int out_size, void* d_ws, size_t ws_size,
                              hipStream_t stream) {
  const float* src  = (const float*)d_in[0];
  const float* Wqkv = (const float*)d_in[1];
  const float* bqkv = (const float*)d_in[2];
  const float* Wo   = (const float*)d_in[3];
  const float* bo   = (const float*)d_in[4];
  const float* W1   = (const float*)d_in[5];
  const float* bf1  = (const float*)d_in[6];
  const float* W2   = (const float*)d_in[7];
  const float* bf2  = (const float*)d_in[8];
  const float* g1   = (const float*)d_in[9];
  const float* be1  = (const float*)d_in[10];
  const float* g2   = (const float*)d_in[11];
  const float* be2  = (const float*)d_in[12];
  float* xout = (float*)d_out;  // fp32 output, written by the final LN

  char* ws = (char*)d_ws;
  size_t off = 0;
  auto alloc = [&](size_t bytes) {
    char* p = ws + off;
    off += (bytes + 255) & ~(size_t)255;
    return p;
  };

  const size_t wq_b = (size_t)L_ * D3 * D_ * 2;
  const size_t wo_b = (size_t)L_ * D_ * D_ * 2;
  const size_t w1_b = (size_t)L_ * DF * D_ * 2;
  const size_t w2_b = (size_t)L_ * D_ * DF * 2;
  const size_t xb_b = (size_t)NT * 512 * 2;  // bf16 residual master
  auto al = [](size_t v) { return (v + 255) & ~(size_t)255; };
  const size_t persist =
      al(wq_b) + al(wo_b) + al(w1_b) + al(w2_b) + al(L_ * D3 * 4) + al(xb_b);

  int CT = NT;
  while (CT > 2048 && persist + (size_t)CT * 5120 + 65536 > ws_size) CT >>= 1;

  __hip_bfloat16* wqkvb = (__hip_bfloat16*)alloc(wq_b);
  __hip_bfloat16* wob   = (__hip_bfloat16*)alloc(wo_b);
  __hip_bfloat16* w1b   = (__hip_bfloat16*)alloc(w1_b);
  __hip_bfloat16* w2b   = (__hip_bfloat16*)alloc(w2_b);
  float*          bqs   = (float*)alloc((size_t)L_ * D3 * 4);
  __hip_bfloat16* xb    = (__hip_bfloat16*)alloc(xb_b);
  __hip_bfloat16* R     = (__hip_bfloat16*)alloc((size_t)CT * 2048 * 2);
  __hip_bfloat16* OB    = (__hip_bfloat16*)alloc((size_t)CT * 512 * 2);

  convw<<<NT * 512 / 4 / 256, 256, 0, stream>>>(src, xb);
  convs<512, 1536, true><<<L_ * D3 * D_ / 4 / 256, 256, 0, stream>>>(Wqkv, wqkvb);
  convs<512, 512, false><<<L_ * D_ * D_ / 4 / 256, 256, 0, stream>>>(Wo, wob);
  convs<512, 2048, false><<<L_ * DF * D_ / 4 / 256, 256, 0, stream>>>(W1, w1b);
  convs<2048, 512, false><<<L_ * D_ * DF / 4 / 256, 256, 0, stream>>>(W2, w2b);
  scaleb<<<L_ * D3 / 256, 256, 0, stream>>>(bqkv, bqs);

  const int nch = NT / CT;
  for (int c = 0; c < nch; ++c) {
    __hip_bfloat16* xm = xb + (size_t)c * CT * 512;
    float* xo = xout + (size_t)c * CT * 512;
    for (int l = 0; l < L_; ++l) {
      // qkv -> R[0 .. CT*1536): 12 x 128-col tiles
      gemm128g<512, 12, false><<<(CT / 128) * 12, 256, 0, stream>>>(
          xm, wqkvb + (size_t)l * D3 * D_, bqs + l * D3, R);
      attn_win<<<CT / 16, 128, 0, stream>>>(R, OB);
      // o-proj -> R[0 .. CT*512): 4 tiles
      gemm128g<512, 4, false><<<(CT / 128) * 4, 256, 0, stream>>>(
          OB, wob + (size_t)l * D_ * D_, bo + l * D_, R);
      ln_res_b<false><<<CT / 4, 256, 0, stream>>>(xm, R, g1 + l * D_,
                                                  be1 + l * D_, xo);
      // ffn1 -> R full: 16 tiles
      gemm128g<512, 16, true><<<(CT / 128) * 16, 256, 0, stream>>>(
          xm, w1b + (size_t)l * DF * D_, bf1 + l * DF, R);
      // ffn2 -> OB: 4 tiles
      gemm128g<2048, 4, false><<<(CT / 128) * 4, 256, 0, stream>>>(
          R, w2b + (size_t)l * D_ * DF, bf2 + l * D_, OB);
      if (l == L_ - 1)
        ln_res_b<true><<<CT / 4, 256, 0, stream>>>(xm, OB, g2 + l * D_,
                                                   be2 + l * D_, xo);
      else
        ln_res_b<false><<<CT / 4, 256, 0, stream>>>(xm, OB, g2 + l * D_,
                                                    be2 + l * D_, xo);
    }
  }
}